// Round 10
// baseline (1398.726 us; speedup 1.0000x reference)
//
#include <hip/hip_runtime.h>

// Problem dims
#define B_   256
#define N_   16000
#define C_   32
#define K_   64
#define T_   124
#define NJ   125      // 128-sample half-window block sums, j = 0..124
#define HID_ 50
#define OUT_ 10

typedef unsigned int u32;

// Exact single f32 ops (prevent fma contraction / reassociation).
__device__ __forceinline__ float fadd(float a, float b) { return __fadd_rn(a, b); }
__device__ __forceinline__ float fmul(float a, float b) { return __fmul_rn(a, b); }
__device__ __forceinline__ float fsub(float a, float b) { return __fsub_rn(a, b); }
// Exact cross-lane bit move (v_readlane ignores exec; lane is a literal).
__device__ __forceinline__ float rdlane(float v, int l) {
    return __uint_as_float(__builtin_amdgcn_readlane(__float_as_uint(v), l));
}

// ---------------------------------------------------------------------------
// Kernel A: conv (SAME pad_lo=31, correlation, sequential-k f32 FMA) + relu +
// numpy-pairwise 128-block sums -> Sg[b][c][j] (f32 global scratch).
// Grid (B, 16): one 1024-sample segment per block; wave w owns channels
// 8w..8w+7. vs round 9: per-ci __syncthreads REMOVED (ybuf is wave-private;
// intra-wave DS ordering + compiler waitcnts are sufficient), tap loads
// scalarized via readfirstlane (s_load on the SMEM pipe, no vmcnt stalls in
// the FMA loop). FMA and reduction orders byte-identical to rounds 8/9.
// ---------------------------------------------------------------------------
__global__ __launch_bounds__(256, 4) void convA(const float* __restrict__ audio,
                                                const float* __restrict__ gt,
                                                float* __restrict__ Sg) {
    __shared__ __align__(16) float abuf[1152];
    __shared__ __align__(16) float ybuf[4][8 * 132];   // per-wave private rows

    const int b = blockIdx.x, g = blockIdx.y;
    const int tid = threadIdx.x, w = tid >> 6, lane = tid & 63;
    const float* arow = audio + (size_t)b * N_;

    const int origin = (g << 10) - 32;
    for (int i = tid; i < 1152; i += 256) {
        int gi = origin + i;
        abuf[i] = (gi >= 0 && gi < N_) ? arow[gi] : 0.0f;
    }
    __syncthreads();                          // the only barrier in this kernel

    for (int ci = 0; ci < 8; ++ci) {
        const int c = (w << 3) + ci;
        const float* kp = gt + ((size_t)__builtin_amdgcn_readfirstlane(c) << 6);
        float kreg[K_];
#pragma unroll
        for (int k = 0; k < K_; ++k) kreg[k] = kp[k];

        for (int pp = 0; pp < 4; ++pp) {
            const int Lb = (pp << 8) + (lane << 2);
            float y0 = 0.0f, y1 = 0.0f, y2 = 0.0f, y3 = 0.0f;
#pragma unroll
            for (int q = 0; q < 17; ++q) {    // k ascending: BLAS order
                float4 A4 = *(const float4*)(abuf + Lb + (q << 2));
                const float av[4] = {A4.x, A4.y, A4.z, A4.w};
#pragma unroll
                for (int e = 0; e < 4; ++e) {
                    const int kb = (q << 2) + e - 1;       // compile-time
                    if (kb     >= 0 && kb     < K_) y0 = fmaf(av[e], kreg[kb    ], y0);
                    if (kb - 1 >= 0 && kb - 1 < K_) y1 = fmaf(av[e], kreg[kb - 1], y1);
                    if (kb - 2 >= 0 && kb - 2 < K_) y2 = fmaf(av[e], kreg[kb - 2], y2);
                    if (kb - 3 >= 0 && kb - 3 < K_) y3 = fmaf(av[e], kreg[kb - 3], y3);
                }
            }
            float4 z;
            z.x = fmaxf(y0, 0.0f); z.y = fmaxf(y1, 0.0f);
            z.z = fmaxf(y2, 0.0f); z.w = fmaxf(y3, 0.0f);
            const int blk = (pp << 1) + (lane >> 5);
            const int posin = (lane & 31) << 2;
            *(float4*)(&ybuf[w][blk * 132 + posin]) = z;
        }
        // numpy pairwise-128 (wave-private ybuf: no barrier needed):
        // r = seq sum of 16 stride-8 elems, then
        // ((r0+r1)+(r2+r3))+((r4+r5)+(r6+r7)) via commutative xor-shuffles
        {
            const int blk8 = lane >> 3, j = lane & 7;
            const float* yb = &ybuf[w][blk8 * 132 + j];
            float r = yb[0];
#pragma unroll
            for (int m = 1; m < 16; ++m) r = fadd(r, yb[m << 3]);
            float v = fadd(r, __shfl_xor(r, 1));
            v = fadd(v, __shfl_xor(v, 2));
            v = fadd(v, __shfl_xor(v, 4));
            const int jg = (g << 3) + blk8;
            if (j == 0 && jg < NJ) Sg[((size_t)b * C_ + c) * NJ + jg] = v;
        }
    }
}

// ---------------------------------------------------------------------------
// Kernel B: SNN. vs round 9:
//  - Bushy currents: 4 t-chains (t0, t0+31, t0+62, t0+93) share each weight
//    row pass -> ONE wr[i] LDS read feeds 4 independent fadd chains (4x ILP,
//    4x less LDS traffic). Each chain's add sequence is unchanged.
//  - Tail: IC/AC weights in registers; spike broadcast via v_readlane (exact
//    bit move) instead of LDS round-trips.
// Grid 256 (one block per b), 256 threads. LDS ~94 KB -> 1 block/CU.
// ---------------------------------------------------------------------------
__global__ __launch_bounds__(256, 1) void snnB(const float* __restrict__ Sg,
                                               const float* __restrict__ Wb,
                                               const float* __restrict__ Wic,
                                               const float* __restrict__ Wac,
                                               float* __restrict__ out) {
    __shared__ float sWb[HID_ * 321];      // 64,200 B (321%32==1: banks spread)
    __shared__ u32   mask[T_ * 10];        //  4,960 B  (AN spike bits per step)
    __shared__ float cur[T_ * HID_];       // 24,800 B  (Bushy pre-currents)

    const int b = blockIdx.x, tid = threadIdx.x;

    for (int i = tid; i < HID_ * 320; i += 256) {
        int r = i / 320;
        sWb[r * 321 + (i - r * 320)] = Wb[i];
    }

    // ---- AN spike bitmasks: word (t, wd) covers i in [32wd, 32wd+32)
    const float* Sb = Sg + (size_t)b * C_ * NJ;
    for (int idx = tid; idx < T_ * 10; idx += 256) {
        int t = idx / 10, wd = idx - t * 10;
        u32 m = 0;
        int c_prev = -1;
        float env = 0.0f;
        for (int k = 0; k < 32; ++k) {
            int i = wd * 32 + k;
            int c = i / 10, s = i - c * 10;
            if (c != c_prev) {
                env = fmul(fadd(Sb[c * NJ + t], Sb[c * NJ + t + 1]), 0.00390625f);
                c_prev = c;
            }
            float sf = (s == 9) ? 1.5f : (float)(0.5 + (double)s * (1.0 / 9.0));
            if (fsub(fmul(env, sf), 0.5f) > 0.0f) m |= (1u << k);
        }
        mask[idx] = m;
    }
    __syncthreads();

    // ---- Bushy currents: 4 chains per weight-row pass (124 = 4*31)
    for (int k = tid; k < 31 * HID_; k += 256) {
        int t0 = k / 50, h = k - t0 * 50;
        const float* wr = sWb + h * 321;
        const u32* m0 = mask + (t0     ) * 10;
        const u32* m1 = mask + (t0 + 31) * 10;
        const u32* m2 = mask + (t0 + 62) * 10;
        const u32* m3 = mask + (t0 + 93) * 10;
        float a0 = 0.0f, a1 = 0.0f, a2 = 0.0f, a3 = 0.0f;
#pragma unroll 8
        for (int i = 0; i < 320; ++i) {
            float wv = wr[i];
            const int wi = i >> 5, sh = i & 31;
            a0 = fadd(a0, ((m0[wi] >> sh) & 1u) ? wv : 0.0f);
            a1 = fadd(a1, ((m1[wi] >> sh) & 1u) ? wv : 0.0f);
            a2 = fadd(a2, ((m2[wi] >> sh) & 1u) ? wv : 0.0f);
            a3 = fadd(a3, ((m3[wi] >> sh) & 1u) ? wv : 0.0f);
        }
        cur[(t0     ) * 50 + h] = a0;
        cur[(t0 + 31) * 50 + h] = a1;
        cur[(t0 + 62) * 50 + h] = a2;
        cur[(t0 + 93) * 50 + h] = a3;
    }
    __syncthreads();

    if (tid >= 64) return;                 // tail runs on wave 0 only

    // ---- sequential 124-step LIF tail, weights in registers
    const int rowic = (tid < HID_) ? tid : HID_ - 1;
    const int rowac = (tid < OUT_) ? tid : OUT_ - 1;
    const int curi  = (tid < HID_) ? tid : HID_ - 1;
    float wic[HID_], wac[HID_];
#pragma unroll
    for (int g = 0; g < HID_; ++g) wic[g] = Wic[rowic * HID_ + g];
#pragma unroll
    for (int g = 0; g < HID_; ++g) wac[g] = Wac[rowac * HID_ + g];

    float memb = 0.0f, memic = 0.0f, memac = 0.0f;
    for (int t = 0; t < T_; ++t) {
        // Bushy LIF (lane h == tid; lanes >=50 duplicate lane 49, unused)
        float mb  = fadd(fmul(0.95f, memb), cur[t * 50 + curi]);
        float spb = (fsub(mb, 1.0f) > 0.0f) ? 1.0f : 0.0f;
        memb = fsub(mb, spb);
        // InferiorColliculus: seq g, spike from lane g via readlane
        float acc = 0.0f;
#pragma unroll
        for (int g = 0; g < HID_; ++g) acc = fadd(acc, fmul(rdlane(spb, g), wic[g]));
        float mi  = fadd(fmul(0.95f, memic), acc);
        float spi = (fsub(mi, 1.0f) > 0.0f) ? 1.0f : 0.0f;
        memic = fsub(mi, spi);
        // AudioCortex
        float ac2 = 0.0f;
#pragma unroll
        for (int g = 0; g < HID_; ++g) ac2 = fadd(ac2, fmul(rdlane(spi, g), wac[g]));
        float ma  = fadd(fmul(0.95f, memac), ac2);
        float spa = (fsub(ma, 1.0f) > 0.0f) ? 1.0f : 0.0f;
        float mo  = fsub(ma, spa);
        memac = mo;
        if (tid < OUT_) {
            size_t base = ((size_t)b * T_ + t) * OUT_ + tid;
            out[base] = spa;
            out[(size_t)(B_ * T_ * OUT_) + base] = mo;
        }
    }
}

// ---------------------------------------------------------------------------
extern "C" void kernel_launch(void* const* d_in, const int* in_sizes, int n_in,
                              void* d_out, int out_size, void* d_ws, size_t ws_size,
                              hipStream_t stream) {
    (void)in_sizes; (void)n_in; (void)out_size; (void)ws_size;
    const float* audio = (const float*)d_in[0];
    const float* gt    = (const float*)d_in[1];
    const float* Wb    = (const float*)d_in[2];
    const float* Wic   = (const float*)d_in[3];
    const float* Wac   = (const float*)d_in[4];

    float* Sg = (float*)d_ws;   // needs 256*32*125*4 = 4,096,000 B of ws

    convA<<<dim3(B_, 16), dim3(256), 0, stream>>>(audio, gt, Sg);
    snnB<<<dim3(B_), dim3(256), 0, stream>>>(Sg, Wb, Wic, Wac, (float*)d_out);
}

// Round 11
// 1192.804 us; speedup vs baseline: 1.1726x; 1.1726x over previous
//
#include <hip/hip_runtime.h>

// Problem dims
#define B_   256
#define N_   16000
#define C_   32
#define K_   64
#define T_   124
#define NJ   125      // 128-sample half-window block sums, j = 0..124
#define HID_ 50
#define OUT_ 10

typedef unsigned int u32;

// Exact single f32 ops (prevent fma contraction / reassociation).
__device__ __forceinline__ float fadd(float a, float b) { return __fadd_rn(a, b); }
__device__ __forceinline__ float fmul(float a, float b) { return __fmul_rn(a, b); }
__device__ __forceinline__ float fsub(float a, float b) { return __fsub_rn(a, b); }
// Exact cross-lane bit move (v_readlane; lane index is a compile-time literal).
__device__ __forceinline__ float rdlane(float v, int l) {
    return __uint_as_float(__builtin_amdgcn_readlane(__float_as_uint(v), l));
}

// ---------------------------------------------------------------------------
// Kernel A: conv (SAME pad_lo=31, correlation, sequential-k f32 FMA) + relu +
// numpy-pairwise 128-block sums -> Sg[b][c][j] (f32 global scratch).
// Grid (B, 16): one 1024-sample segment per block; wave w owns channels
// 8w..8w+7.
// vs round 10 (1206 us, 3.5 GB fetch / 983 MB write = scratch spills):
//  - tap loads back to round-9's per-lane vector form (no readfirstlane);
//  - __launch_bounds__(256, 2): 256-VGPR budget so kreg[64] stays resident
//    (round 9/10's (256,4) era pinned VGPR=64 -> taps could never live in
//    registers; r9 re-read them from L1 (vmcnt stalls), r10 spilled).
// Keeps round-10's validated wins: no inner barriers (ybuf is wave-private;
// intra-wave DS ordering suffices — r10 passed correctness), grid (B,16).
// FMA and reduction orders byte-identical to rounds 8/9/10.
// ---------------------------------------------------------------------------
__global__ __launch_bounds__(256, 2) void convA(const float* __restrict__ audio,
                                                const float* __restrict__ gt,
                                                float* __restrict__ Sg) {
    __shared__ __align__(16) float abuf[1152];
    __shared__ __align__(16) float ybuf[4][8 * 132];   // per-wave private rows

    const int b = blockIdx.x, g = blockIdx.y;
    const int tid = threadIdx.x, w = tid >> 6, lane = tid & 63;
    const float* arow = audio + (size_t)b * N_;

    const int origin = (g << 10) - 32;
    for (int i = tid; i < 1152; i += 256) {
        int gi = origin + i;
        abuf[i] = (gi >= 0 && gi < N_) ? arow[gi] : 0.0f;
    }
    __syncthreads();                          // the only barrier in this kernel

    for (int ci = 0; ci < 8; ++ci) {
        const int c = (w << 3) + ci;
        float kreg[K_];
#pragma unroll
        for (int k = 0; k < K_; ++k) kreg[k] = gt[(c << 6) + k];

        for (int pp = 0; pp < 4; ++pp) {
            const int Lb = (pp << 8) + (lane << 2);
            float y0 = 0.0f, y1 = 0.0f, y2 = 0.0f, y3 = 0.0f;
#pragma unroll
            for (int q = 0; q < 17; ++q) {    // k ascending: BLAS order
                float4 A4 = *(const float4*)(abuf + Lb + (q << 2));
                const float av[4] = {A4.x, A4.y, A4.z, A4.w};
#pragma unroll
                for (int e = 0; e < 4; ++e) {
                    const int kb = (q << 2) + e - 1;       // compile-time
                    if (kb     >= 0 && kb     < K_) y0 = fmaf(av[e], kreg[kb    ], y0);
                    if (kb - 1 >= 0 && kb - 1 < K_) y1 = fmaf(av[e], kreg[kb - 1], y1);
                    if (kb - 2 >= 0 && kb - 2 < K_) y2 = fmaf(av[e], kreg[kb - 2], y2);
                    if (kb - 3 >= 0 && kb - 3 < K_) y3 = fmaf(av[e], kreg[kb - 3], y3);
                }
            }
            float4 z;
            z.x = fmaxf(y0, 0.0f); z.y = fmaxf(y1, 0.0f);
            z.z = fmaxf(y2, 0.0f); z.w = fmaxf(y3, 0.0f);
            const int blk = (pp << 1) + (lane >> 5);
            const int posin = (lane & 31) << 2;
            *(float4*)(&ybuf[w][blk * 132 + posin]) = z;
        }
        // numpy pairwise-128 (wave-private ybuf: no barrier needed):
        // r = seq sum of 16 stride-8 elems, then
        // ((r0+r1)+(r2+r3))+((r4+r5)+(r6+r7)) via commutative xor-shuffles
        {
            const int blk8 = lane >> 3, j = lane & 7;
            const float* yb = &ybuf[w][blk8 * 132 + j];
            float r = yb[0];
#pragma unroll
            for (int m = 1; m < 16; ++m) r = fadd(r, yb[m << 3]);
            float v = fadd(r, __shfl_xor(r, 1));
            v = fadd(v, __shfl_xor(v, 2));
            v = fadd(v, __shfl_xor(v, 4));
            const int jg = (g << 3) + blk8;
            if (j == 0 && jg < NJ) Sg[((size_t)b * C_ + c) * NJ + jg] = v;
        }
    }
}

// ---------------------------------------------------------------------------
// Kernel B: SNN (unchanged from round 10 — measured ~190 us).
// AN spikes precomputed as bitmasks; 6200 independent (t,h) Bushy chains run
// in parallel, 4 t-chains per weight-row pass (one LDS read feeds 4 fadd
// chains; bit-exact: fadd(acc, bit ? w : +0.f) == fadd(acc, fmul(s,w))).
// Sequential 124-step LIF tail on wave 0 with register weights + readlane.
// ---------------------------------------------------------------------------
__global__ __launch_bounds__(256, 1) void snnB(const float* __restrict__ Sg,
                                               const float* __restrict__ Wb,
                                               const float* __restrict__ Wic,
                                               const float* __restrict__ Wac,
                                               float* __restrict__ out) {
    __shared__ float sWb[HID_ * 321];      // 64,200 B (321%32==1: banks spread)
    __shared__ u32   mask[T_ * 10];        //  4,960 B  (AN spike bits per step)
    __shared__ float cur[T_ * HID_];       // 24,800 B  (Bushy pre-currents)

    const int b = blockIdx.x, tid = threadIdx.x;

    for (int i = tid; i < HID_ * 320; i += 256) {
        int r = i / 320;
        sWb[r * 321 + (i - r * 320)] = Wb[i];
    }

    // ---- AN spike bitmasks: word (t, wd) covers i in [32wd, 32wd+32)
    const float* Sb = Sg + (size_t)b * C_ * NJ;
    for (int idx = tid; idx < T_ * 10; idx += 256) {
        int t = idx / 10, wd = idx - t * 10;
        u32 m = 0;
        int c_prev = -1;
        float env = 0.0f;
        for (int k = 0; k < 32; ++k) {
            int i = wd * 32 + k;
            int c = i / 10, s = i - c * 10;
            if (c != c_prev) {
                env = fmul(fadd(Sb[c * NJ + t], Sb[c * NJ + t + 1]), 0.00390625f);
                c_prev = c;
            }
            float sf = (s == 9) ? 1.5f : (float)(0.5 + (double)s * (1.0 / 9.0));
            if (fsub(fmul(env, sf), 0.5f) > 0.0f) m |= (1u << k);
        }
        mask[idx] = m;
    }
    __syncthreads();

    // ---- Bushy currents: 4 chains per weight-row pass (124 = 4*31)
    for (int k = tid; k < 31 * HID_; k += 256) {
        int t0 = k / 50, h = k - t0 * 50;
        const float* wr = sWb + h * 321;
        const u32* m0 = mask + (t0     ) * 10;
        const u32* m1 = mask + (t0 + 31) * 10;
        const u32* m2 = mask + (t0 + 62) * 10;
        const u32* m3 = mask + (t0 + 93) * 10;
        float a0 = 0.0f, a1 = 0.0f, a2 = 0.0f, a3 = 0.0f;
#pragma unroll 8
        for (int i = 0; i < 320; ++i) {
            float wv = wr[i];
            const int wi = i >> 5, sh = i & 31;
            a0 = fadd(a0, ((m0[wi] >> sh) & 1u) ? wv : 0.0f);
            a1 = fadd(a1, ((m1[wi] >> sh) & 1u) ? wv : 0.0f);
            a2 = fadd(a2, ((m2[wi] >> sh) & 1u) ? wv : 0.0f);
            a3 = fadd(a3, ((m3[wi] >> sh) & 1u) ? wv : 0.0f);
        }
        cur[(t0     ) * 50 + h] = a0;
        cur[(t0 + 31) * 50 + h] = a1;
        cur[(t0 + 62) * 50 + h] = a2;
        cur[(t0 + 93) * 50 + h] = a3;
    }
    __syncthreads();

    if (tid >= 64) return;                 // tail runs on wave 0 only

    // ---- sequential 124-step LIF tail, weights in registers
    const int rowic = (tid < HID_) ? tid : HID_ - 1;
    const int rowac = (tid < OUT_) ? tid : OUT_ - 1;
    const int curi  = (tid < HID_) ? tid : HID_ - 1;
    float wic[HID_], wac[HID_];
#pragma unroll
    for (int g = 0; g < HID_; ++g) wic[g] = Wic[rowic * HID_ + g];
#pragma unroll
    for (int g = 0; g < HID_; ++g) wac[g] = Wac[rowac * HID_ + g];

    float memb = 0.0f, memic = 0.0f, memac = 0.0f;
    for (int t = 0; t < T_; ++t) {
        // Bushy LIF (lane h == tid; lanes >=50 duplicate lane 49, unused)
        float mb  = fadd(fmul(0.95f, memb), cur[t * 50 + curi]);
        float spb = (fsub(mb, 1.0f) > 0.0f) ? 1.0f : 0.0f;
        memb = fsub(mb, spb);
        // InferiorColliculus: seq g, spike from lane g via readlane
        float acc = 0.0f;
#pragma unroll
        for (int g = 0; g < HID_; ++g) acc = fadd(acc, fmul(rdlane(spb, g), wic[g]));
        float mi  = fadd(fmul(0.95f, memic), acc);
        float spi = (fsub(mi, 1.0f) > 0.0f) ? 1.0f : 0.0f;
        memic = fsub(mi, spi);
        // AudioCortex
        float ac2 = 0.0f;
#pragma unroll
        for (int g = 0; g < HID_; ++g) ac2 = fadd(ac2, fmul(rdlane(spi, g), wac[g]));
        float ma  = fadd(fmul(0.95f, memac), ac2);
        float spa = (fsub(ma, 1.0f) > 0.0f) ? 1.0f : 0.0f;
        float mo  = fsub(ma, spa);
        memac = mo;
        if (tid < OUT_) {
            size_t base = ((size_t)b * T_ + t) * OUT_ + tid;
            out[base] = spa;
            out[(size_t)(B_ * T_ * OUT_) + base] = mo;
        }
    }
}

// ---------------------------------------------------------------------------
extern "C" void kernel_launch(void* const* d_in, const int* in_sizes, int n_in,
                              void* d_out, int out_size, void* d_ws, size_t ws_size,
                              hipStream_t stream) {
    (void)in_sizes; (void)n_in; (void)out_size; (void)ws_size;
    const float* audio = (const float*)d_in[0];
    const float* gt    = (const float*)d_in[1];
    const float* Wb    = (const float*)d_in[2];
    const float* Wic   = (const float*)d_in[3];
    const float* Wac   = (const float*)d_in[4];

    float* Sg = (float*)d_ws;   // needs 256*32*125*4 = 4,096,000 B of ws

    convA<<<dim3(B_, 16), dim3(256), 0, stream>>>(audio, gt, Sg);
    snnB<<<dim3(B_), dim3(256), 0, stream>>>(Sg, Wb, Wic, Wac, (float*)d_out);
}